// Round 11
// baseline (15980.598 us; speedup 1.0000x reference)
//
#include <hip/hip_runtime.h>
#include <hip/hip_bf16.h>

typedef __attribute__((ext_vector_type(8))) short bf16x8;
typedef __attribute__((ext_vector_type(4))) float f32x4;
typedef __attribute__((ext_vector_type(4))) unsigned int u32x4;
typedef unsigned short u16;
typedef unsigned int u32;

__device__ __forceinline__ u16 f2bf(float f) {
  union { float f; unsigned u; } v; v.f = f;
  unsigned r = v.u + 0x7FFFu + ((v.u >> 16) & 1u);   // RTNE
  return (u16)(r >> 16);
}

__device__ __forceinline__ float sigm_fast(float x) {
  return __builtin_amdgcn_rcpf(1.f + __expf(-x));
}
__device__ __forceinline__ float tanh_fast(float x) {
  x = fminf(fmaxf(x, -15.f), 15.f);
  float e = __expf(2.f * x);
  return (e - 1.f) * __builtin_amdgcn_rcpf(e + 1.f);
}

// coherent (LLC) loads/stores, untracked by compiler -> caller must waitcnt
__device__ __forceinline__ void ld_llc_b128(const u16* p, bf16x8& r) {
  asm volatile("global_load_dwordx4 %0, %1, off sc0 sc1" : "=&v"(r) : "v"(p));
}
__device__ __forceinline__ void ld_llc_4x32(const u32* p, u32x4& r) {
  asm volatile("global_load_dwordx4 %0, %1, off sc0 sc1" : "=&v"(r) : "v"(p));
}
__device__ __forceinline__ void st_llc_b16(u16* p, u32 v) {
  asm volatile("global_store_short %0, %1, off sc0 sc1"
               :: "v"(p), "v"(v) : "memory");
}

// ---------------------------------------------------------------------------
// fold (all 4 gates, z = gate): Wt[(j*4+g)][k] = sum_m P[m][j]*(W[k][m]*cos(rx[m]))
// ---------------------------------------------------------------------------
__global__ __launch_bounds__(256) void fold_kernel(
    const float* __restrict__ W0, const float* __restrict__ rx0, const float* __restrict__ P0,
    const float* __restrict__ W1, const float* __restrict__ rx1, const float* __restrict__ P1,
    const float* __restrict__ W2, const float* __restrict__ rx2, const float* __restrict__ P2,
    const float* __restrict__ W3, const float* __restrict__ rx3, const float* __restrict__ P3,
    u16* __restrict__ Wt)
{
  const int g = blockIdx.z;
  const float* W  = (g == 0) ? W0  : (g == 1) ? W1  : (g == 2) ? W2  : W3;
  const float* rx = (g == 0) ? rx0 : (g == 1) ? rx1 : (g == 2) ? rx2 : rx3;
  const float* P  = (g == 0) ? P0  : (g == 1) ? P1  : (g == 2) ? P2  : P3;
  __shared__ __align__(16) float As[16][68];
  __shared__ __align__(16) float Bs[16][68];
  const int bk = blockIdx.x, bj = blockIdx.y;
  const int tid = threadIdx.x;
  const int tx = tid & 15, ty = tid >> 4;
  const int j0 = bj * 64, k0 = bk * 64;
  float acc[4][4] = {};
  for (int m0 = 0; m0 < 512; m0 += 16) {
#pragma unroll
    for (int l = 0; l < 4; ++l) {
      int lin = tid + 256 * l;
      int mm = lin >> 6, jr = lin & 63;
      As[mm][jr] = P[(m0 + mm) * 512 + j0 + jr];
      int kk = lin >> 4, mb = lin & 15;
      Bs[mb][kk] = W[(k0 + kk) * 512 + m0 + mb] * cosf(rx[m0 + mb]);
    }
    __syncthreads();
#pragma unroll
    for (int mm = 0; mm < 16; ++mm) {
      f32x4 a = *(const f32x4*)&As[mm][ty * 4];
      f32x4 b = *(const f32x4*)&Bs[mm][tx * 4];
#pragma unroll
      for (int i = 0; i < 4; ++i)
#pragma unroll
        for (int jj = 0; jj < 4; ++jj)
          acc[i][jj] += a[i] * b[jj];
    }
    __syncthreads();
  }
#pragma unroll
  for (int i = 0; i < 4; ++i) {
    int j = j0 + ty * 4 + i;
    size_t n = (size_t)(j * 4 + g);
    ushort4 w;
    w.x = f2bf(acc[i][0]); w.y = f2bf(acc[i][1]);
    w.z = f2bf(acc[i][2]); w.w = f2bf(acc[i][3]);
    *(ushort4*)(Wt + n * 1024 + k0 + tx * 4) = w;
  }
}

// bpn[j*4+g]; grid 32 = 4 gates x 8 j-blocks
__global__ __launch_bounds__(256) void fold_bias(
    const float* __restrict__ b0, const float* __restrict__ rx0, const float* __restrict__ P0,
    const float* __restrict__ b1, const float* __restrict__ rx1, const float* __restrict__ P1,
    const float* __restrict__ b2, const float* __restrict__ rx2, const float* __restrict__ P2,
    const float* __restrict__ b3, const float* __restrict__ rx3, const float* __restrict__ P3,
    float* __restrict__ bpn)
{
  const int g = blockIdx.x >> 3, jb = blockIdx.x & 7;
  const float* b  = (g == 0) ? b0  : (g == 1) ? b1  : (g == 2) ? b2  : b3;
  const float* rx = (g == 0) ? rx0 : (g == 1) ? rx1 : (g == 2) ? rx2 : rx3;
  const float* P  = (g == 0) ? P0  : (g == 1) ? P1  : (g == 2) ? P2  : P3;
  __shared__ float bc[512];
  __shared__ float red[4][65];
  const int tid = threadIdx.x;
  bc[tid] = b[tid] * cosf(rx[tid]);
  bc[tid + 256] = b[tid + 256] * cosf(rx[tid + 256]);
  __syncthreads();
  const int jl = tid & 63, msub = tid >> 6;
  const int j = jb * 64 + jl;
  float acc = 0.f;
  for (int m = msub * 128; m < msub * 128 + 128; ++m)
    acc += bc[m] * P[m * 512 + j];
  red[msub][jl] = acc;
  __syncthreads();
  if (msub == 0)
    bpn[j * 4 + g] = red[0][jl] + red[1][jl] + red[2][jl] + red[3][jl];
}

__global__ __launch_bounds__(256) void xcvt_kernel(
    const float* __restrict__ x, u16* __restrict__ xb)
{
  size_t i = (size_t)blockIdx.x * 256 + threadIdx.x;
  f32x4 v = *(const f32x4*)(x + i * 4);
  ushort4 w;
  w.x = f2bf(v[0]); w.y = f2bf(v[1]); w.z = f2bf(v[2]); w.w = f2bf(v[3]);
  *(ushort4*)(xb + i * 4) = w;
}

// zero hbuf + cbuf + counters, every launch (replay determinism)
__global__ __launch_bounds__(256) void init_kernel(unsigned* hbuf32, float* cbuf,
                                                   unsigned* ctrs) {
  int i = blockIdx.x * 256 + threadIdx.x;      // 65536
  hbuf32[i] = 0;
  cbuf[i] = 0.f;
  if (i < 32) ctrs[i] = 0;
}

__global__ __launch_bounds__(256) void tail_kernel(
    const float* __restrict__ hlast, const float* __restrict__ c,
    float* __restrict__ hx, float* __restrict__ cx)
{
  int i = blockIdx.x * 256 + threadIdx.x;
  hx[i] = hlast[i];
  cx[i] = c[i];
}

// ---------------------------------------------------------------------------
// fallback single-step kernel (R1-proven; row-major h layout, self-consistent)
// ---------------------------------------------------------------------------
__global__ __launch_bounds__(256) void step_kernel(
    const u16* __restrict__ xb_t, const u16* __restrict__ h_in,
    u16* __restrict__ h_out, const u16* __restrict__ Wt,
    const float* __restrict__ bpn, float* __restrict__ cbuf,
    float* __restrict__ out_t)
{
  __shared__ float pre_s[32][33];
  const int bid = blockIdx.x;
  const int mb = bid >> 6, nb = bid & 63;
  const int b0 = mb * 32, n0 = nb * 32;
  const int tid = threadIdx.x;
  const int wv = tid >> 6, lane = tid & 63;
  const int rt = wv >> 1, nt = wv & 1;
  const int l15 = lane & 15, kg = lane >> 4;
  const int brow = b0 + rt * 16 + l15;
  const int ncol = n0 + nt * 16 + l15;
  const u16* wrow = Wt + (size_t)ncol * 1024;
  const u16* xrow = xb_t + (size_t)brow * 512;
  const u16* hrow = h_in + (size_t)brow * 512;
  f32x4 acc = {0.f, 0.f, 0.f, 0.f};
#pragma unroll 8
  for (int kk = 0; kk < 32; ++kk) {
    const int kb = kk * 32 + kg * 8;
    bf16x8 bfrag = *(const bf16x8*)(wrow + kb);
    bf16x8 afrag;
    if (kb < 512) afrag = *(const bf16x8*)(xrow + kb);
    else          afrag = *(const bf16x8*)(hrow + (kb - 512));
    acc = __builtin_amdgcn_mfma_f32_16x16x32_bf16(afrag, bfrag, acc, 0, 0, 0);
  }
  const float bias = bpn[ncol];
#pragma unroll
  for (int q = 0; q < 4; ++q)
    pre_s[rt * 16 + kg * 4 + q][nt * 16 + l15] = acc[q] + bias;
  __syncthreads();
  const int bb = tid >> 3, jo = tid & 7;
  float pf = pre_s[bb][jo * 4 + 0];
  float pi = pre_s[bb][jo * 4 + 1];
  float pu = pre_s[bb][jo * 4 + 2];
  float po = pre_s[bb][jo * 4 + 3];
  float fg = 1.f / (1.f + __expf(-pf));
  float ig = 1.f / (1.f + __expf(-pi));
  float gg = tanhf(pu);
  float og = 1.f / (1.f + __expf(-po));
  size_t idx = (size_t)(b0 + bb) * 512 + (size_t)(nb * 8 + jo);
  float cv = fg * cbuf[idx] + ig * gg;
  cbuf[idx] = cv;
  float hv = og * tanhf(cv);
  out_t[idx] = hv;
  h_out[idx] = f2bf(hv);
}

// ---------------------------------------------------------------------------
// persistent recurrence v5: 1024 wgs x 64 threads (ONE WAVE per wg, NO
// barriers in the loop). 8 row-clusters x 128 col-blocks. Blocked h layout
// hblk[2][8][64][16][8] bf16: wg's store = one 256B region; consumer
// fragment = 16B contiguous (fully-coalesced 4KB per load instr).
// Per-cluster sync = 4-way-split counter (32 adds each), polled as one
// dwordx4. 4 independent MFMA acc chains hide MFMA latency on the lone wave.
// ---------------------------------------------------------------------------
__global__ __launch_bounds__(64, 1) void qlstm_persistent(
    const u16* __restrict__ Xbf,    // [256][128][512] bf16
    u16* __restrict__ hblk,         // [2][8][64][16][8] bf16
    const u16* __restrict__ Wt,     // [2048][1024] bf16, n = j*4+g
    const float* __restrict__ bpn,  // [2048] f32
    float* __restrict__ out,        // [256][128][512] + hx + cx
    u32* __restrict__ ctrs)         // [8][4]
{
  __shared__ float pre_s[16][20];
  const int bid = blockIdx.x;        // 0..1023
  const int cl  = bid >> 7;          // row-cluster 0..7 (16 rows)
  const int cb  = bid & 127;         // col-block (16 gate cols)
  const int l   = threadIdx.x;       // 0..63
  const int l15 = l & 15;
  const int kg  = l >> 4;            // 0..3
  const int n0  = cb * 16;
  const int ncol = n0 + l15;
  const int arow = cl * 16 + l15;    // A-fragment global row

  // W fragments, full K=1024 (128 VGPR), resident for all 256 steps
  const u16* wrowp = Wt + (size_t)ncol * 1024;
  bf16x8 wreg[32];
#pragma unroll
  for (int kk = 0; kk < 32; ++kk)
    wreg[kk] = *(const bf16x8*)(wrowp + kk * 32 + kg * 8);
  const float bnc = bpn[ncol];

  // worker mapping for gates/cell: lane -> (row = l&15, j = l>>4)
  const int wj = kg;                     // local j 0..3
  const int jglob = cb * 4 + wj;         // global h-col
  const size_t eidx = (size_t)(cl * 16 + l15) * 512 + (size_t)jglob;
  const size_t hoff = (size_t)cl * 8192 + (size_t)(jglob >> 3) * 128
                    + (size_t)l15 * 8 + (size_t)(jglob & 7);
  float cst = 0.f, hl = 0.f;

  // x prefetch for t=0 (plain, compiler-tracked)
  bf16x8 xf[16];
  const u16* xrp = Xbf + (size_t)arow * 512;
#pragma unroll
  for (int kk = 0; kk < 16; ++kk)
    xf[kk] = *(const bf16x8*)(xrp + kk * 32 + kg * 8);

  for (int t = 0; t < 256; ++t) {
    // ---- poll cluster counter (skip t=0) ----
    if (t > 0) {
      const u32 target = 128u * (u32)t;
      const u32* cp = ctrs + cl * 4;
      int guard = 0;
      for (;;) {
        u32x4 c4;
        ld_llc_4x32(cp, c4);
        asm volatile("s_waitcnt vmcnt(0)" ::: "memory");
        if (c4[0] + c4[1] + c4[2] + c4[3] >= target) break;
        __builtin_amdgcn_s_sleep(1);
        if (++guard > 8000) break;           // bounded: fail loudly, no hang
      }
      asm volatile("" ::: "memory");
    }

    // ---- issue coherent h loads (blocked layout, coalesced) ----
    bf16x8 hf[16];
    if (t > 0) {
      const u16* hb = hblk + (size_t)((t & 1) ? 65536 : 0) + (size_t)cl * 8192;
#pragma unroll
      for (int kk = 0; kk < 16; ++kk)
        ld_llc_b128(hb + (size_t)(kk * 4 + kg) * 128 + (size_t)l15 * 8, hf[kk]);
    }

    // ---- x-MFMAs (register-ready) hide h-load tail; 4 acc chains ----
    f32x4 a0 = {0,0,0,0}, a1 = {0,0,0,0}, a2 = {0,0,0,0}, a3 = {0,0,0,0};
#pragma unroll
    for (int kk = 0; kk < 16; kk += 4) {
      a0 = __builtin_amdgcn_mfma_f32_16x16x32_bf16(xf[kk+0], wreg[kk+0], a0, 0, 0, 0);
      a1 = __builtin_amdgcn_mfma_f32_16x16x32_bf16(xf[kk+1], wreg[kk+1], a1, 0, 0, 0);
      a2 = __builtin_amdgcn_mfma_f32_16x16x32_bf16(xf[kk+2], wreg[kk+2], a2, 0, 0, 0);
      a3 = __builtin_amdgcn_mfma_f32_16x16x32_bf16(xf[kk+3], wreg[kk+3], a3, 0, 0, 0);
    }
    if (t > 0) {
      asm volatile("s_waitcnt vmcnt(0)" ::: "memory");
      __builtin_amdgcn_sched_barrier(0);
#pragma unroll
      for (int kk = 0; kk < 16; kk += 4) {
        a0 = __builtin_amdgcn_mfma_f32_16x16x32_bf16(hf[kk+0], wreg[16+kk+0], a0, 0, 0, 0);
        a1 = __builtin_amdgcn_mfma_f32_16x16x32_bf16(hf[kk+1], wreg[16+kk+1], a1, 0, 0, 0);
        a2 = __builtin_amdgcn_mfma_f32_16x16x32_bf16(hf[kk+2], wreg[16+kk+2], a2, 0, 0, 0);
        a3 = __builtin_amdgcn_mfma_f32_16x16x32_bf16(hf[kk+3], wreg[16+kk+3], a3, 0, 0, 0);
      }
    }
    f32x4 acc = (a0 + a1) + (a2 + a3);

    // ---- single-wave gate transpose via LDS (lgkmcnt only, no barrier) ----
    // C/D layout: col = l&15, row = kg*4+q
#pragma unroll
    for (int q = 0; q < 4; ++q)
      pre_s[kg * 4 + q][l15] = acc[q] + bnc;
    asm volatile("s_waitcnt lgkmcnt(0)" ::: "memory");
    __builtin_amdgcn_sched_barrier(0);
    f32x4 g4 = *(const f32x4*)&pre_s[l15][wj * 4];
    asm volatile("s_waitcnt lgkmcnt(0)" ::: "memory");
    __builtin_amdgcn_sched_barrier(0);

    cst = sigm_fast(g4[0]) * cst + sigm_fast(g4[1]) * tanh_fast(g4[2]);
    float hv = sigm_fast(g4[3]) * tanh_fast(cst);
    hl = hv;

    // ---- coherent h store (256B region per wg) + drain + counter add ----
    u16* hw = hblk + (size_t)(((t + 1) & 1) ? 65536 : 0) + hoff;
    st_llc_b16(hw, (u32)f2bf(hv));
    asm volatile("s_waitcnt vmcnt(0)" ::: "memory");
    if (l == 0)
      __hip_atomic_fetch_add(ctrs + cl * 4 + (cb & 3), 1u,
                             __ATOMIC_RELAXED, __HIP_MEMORY_SCOPE_AGENT);

    // off-critical-path: out store + x prefetch for t+1
    out[(size_t)t * 65536 + eidx] = hv;
    if (t < 255) {
      const u16* xr = Xbf + (size_t)(t + 1) * 65536 + (size_t)arow * 512;
#pragma unroll
      for (int kk = 0; kk < 16; ++kk)
        xf[kk] = *(const bf16x8*)(xr + kk * 32 + kg * 8);
    }
  }

  out[(size_t)256 * 65536 + eidx] = hl;
  out[(size_t)256 * 65536 + 65536 + eidx] = cst;
}

// ---------------------------------------------------------------------------
extern "C" void kernel_launch(void* const* d_in, const int* in_sizes, int n_in,
                              void* d_out, int out_size, void* d_ws, size_t ws_size,
                              hipStream_t stream) {
  (void)in_sizes; (void)n_in; (void)out_size; (void)ws_size;
  const float* inp = (const float*)d_in[0];
  float* out = (float*)d_out;

  char* base = (char*)d_ws;
  u16*      Xbf   = (u16*)base;
  u16*      Wt    = (u16*)(base + 33554432);
  float*    bpn   = (float*)(base + 33554432 + 4194304);
  u16*      hbuf  = (u16*)(base + 33554432 + 4194304 + 8192);
  unsigned* ctrs  = (unsigned*)(base + 33554432 + 4194304 + 8192 + 262144);
  float*    cbuf  = (float*)(base + 33554432 + 4194304 + 8192 + 262144 + 1024);

  const float* W[4];  const float* b[4];  const float* rx[4];  const float* P[4];
  for (int g = 0; g < 4; ++g) {
    W[g]  = (const float*)d_in[1 + 4 * g];
    b[g]  = (const float*)d_in[2 + 4 * g];
    rx[g] = (const float*)d_in[3 + 4 * g];
    P[g]  = (const float*)d_in[4 + 4 * g];
  }
  fold_kernel<<<dim3(16, 8, 4), 256, 0, stream>>>(
      W[0], rx[0], P[0], W[1], rx[1], P[1],
      W[2], rx[2], P[2], W[3], rx[3], P[3], Wt);
  fold_bias<<<dim3(32), 256, 0, stream>>>(
      b[0], rx[0], P[0], b[1], rx[1], P[1],
      b[2], rx[2], P[2], b[3], rx[3], P[3], bpn);
  xcvt_kernel<<<16384, 256, 0, stream>>>(inp, Xbf);
  init_kernel<<<256, 256, 0, stream>>>((unsigned*)hbuf, cbuf, ctrs);

  void* args[6];
  const u16* Xbf_c = Xbf;
  const u16* Wt_c = Wt;
  const float* bpn_c = bpn;
  u16* hbuf_p = hbuf;
  float* out_p = out;
  u32* ctrs_p = ctrs;
  args[0] = (void*)&Xbf_c;
  args[1] = (void*)&hbuf_p;
  args[2] = (void*)&Wt_c;
  args[3] = (void*)&bpn_c;
  args[4] = (void*)&out_p;
  args[5] = (void*)&ctrs_p;
  hipError_t e = hipLaunchCooperativeKernel((const void*)qlstm_persistent,
                                            dim3(1024), dim3(64), args, 0, stream);
  if (e != hipSuccess) {
    // fallback: proven multi-launch path (row-major h layout, self-consistent)
    for (int t = 0; t < 256; ++t) {
      const u16* xb_t  = Xbf + (size_t)t * 65536;
      const u16* h_in  = hbuf + (size_t)(t & 1) * 65536;
      u16*       h_oup = hbuf + (size_t)((t & 1) ^ 1) * 65536;
      float*     out_t = out + (size_t)t * 65536;
      step_kernel<<<256, 256, 0, stream>>>(xb_t, h_in, h_oup, Wt, bpn, cbuf, out_t);
    }
    tail_kernel<<<256, 256, 0, stream>>>(out + (size_t)255 * 65536, cbuf,
                                         out + (size_t)256 * 65536,
                                         out + (size_t)256 * 65536 + 65536);
  }
}

// Round 12
// 1402.876 us; speedup vs baseline: 11.3913x; 11.3913x over previous
//
#include <hip/hip_runtime.h>
#include <hip/hip_bf16.h>

typedef __attribute__((ext_vector_type(8))) short bf16x8;
typedef __attribute__((ext_vector_type(4))) float f32x4;
typedef unsigned short u16;
typedef unsigned int u32;

__device__ __forceinline__ u16 f2bf(float f) {
  union { float f; unsigned u; } v; v.f = f;
  unsigned r = v.u + 0x7FFFu + ((v.u >> 16) & 1u);   // RTNE
  return (u16)(r >> 16);
}

__device__ __forceinline__ float sigm_fast(float x) {
  return __builtin_amdgcn_rcpf(1.f + __expf(-x));
}
__device__ __forceinline__ float tanh_fast(float x) {
  x = fminf(fmaxf(x, -15.f), 15.f);
  float e = __expf(2.f * x);
  return (e - 1.f) * __builtin_amdgcn_rcpf(e + 1.f);
}

// ---- untracked (inline-asm) memory ops: caller owns the vmcnt ledger ----
__device__ __forceinline__ void ld_llc_b128(const u16* p, bf16x8& r) {  // coherent
  asm volatile("global_load_dwordx4 %0, %1, off sc0 sc1" : "=&v"(r) : "v"(p));
}
__device__ __forceinline__ void ld_g_b128(const u16* p, bf16x8& r) {    // cached
  asm volatile("global_load_dwordx4 %0, %1, off" : "=&v"(r) : "v"(p));
}
__device__ __forceinline__ void st_llc_b32(u32* p, u32 v) {             // coherent
  asm volatile("global_store_dword %0, %1, off sc0 sc1" :: "v"(p), "v"(v) : "memory");
}
__device__ __forceinline__ void st_g_b32(u32* p, u32 v) {               // cached
  asm volatile("global_store_dword %0, %1, off" :: "v"(p), "v"(v) : "memory");
}

// ---------------------------------------------------------------------------
// fold (all 4 gates, z = gate): Wt[(j*4+g)][k] = sum_m P[m][j]*(W[k][m]*cos(rx[m]))
// ---------------------------------------------------------------------------
__global__ __launch_bounds__(256) void fold_kernel(
    const float* __restrict__ W0, const float* __restrict__ rx0, const float* __restrict__ P0,
    const float* __restrict__ W1, const float* __restrict__ rx1, const float* __restrict__ P1,
    const float* __restrict__ W2, const float* __restrict__ rx2, const float* __restrict__ P2,
    const float* __restrict__ W3, const float* __restrict__ rx3, const float* __restrict__ P3,
    u16* __restrict__ Wt)
{
  const int g = blockIdx.z;
  const float* W  = (g == 0) ? W0  : (g == 1) ? W1  : (g == 2) ? W2  : W3;
  const float* rx = (g == 0) ? rx0 : (g == 1) ? rx1 : (g == 2) ? rx2 : rx3;
  const float* P  = (g == 0) ? P0  : (g == 1) ? P1  : (g == 2) ? P2  : P3;
  __shared__ __align__(16) float As[16][68];
  __shared__ __align__(16) float Bs[16][68];
  const int bk = blockIdx.x, bj = blockIdx.y;
  const int tid = threadIdx.x;
  const int tx = tid & 15, ty = tid >> 4;
  const int j0 = bj * 64, k0 = bk * 64;
  float acc[4][4] = {};
  for (int m0 = 0; m0 < 512; m0 += 16) {
#pragma unroll
    for (int l = 0; l < 4; ++l) {
      int lin = tid + 256 * l;
      int mm = lin >> 6, jr = lin & 63;
      As[mm][jr] = P[(m0 + mm) * 512 + j0 + jr];
      int kk = lin >> 4, mb = lin & 15;
      Bs[mb][kk] = W[(k0 + kk) * 512 + m0 + mb] * cosf(rx[m0 + mb]);
    }
    __syncthreads();
#pragma unroll
    for (int mm = 0; mm < 16; ++mm) {
      f32x4 a = *(const f32x4*)&As[mm][ty * 4];
      f32x4 b = *(const f32x4*)&Bs[mm][tx * 4];
#pragma unroll
      for (int i = 0; i < 4; ++i)
#pragma unroll
        for (int jj = 0; jj < 4; ++jj)
          acc[i][jj] += a[i] * b[jj];
    }
    __syncthreads();
  }
#pragma unroll
  for (int i = 0; i < 4; ++i) {
    int j = j0 + ty * 4 + i;
    size_t n = (size_t)(j * 4 + g);
    ushort4 w;
    w.x = f2bf(acc[i][0]); w.y = f2bf(acc[i][1]);
    w.z = f2bf(acc[i][2]); w.w = f2bf(acc[i][3]);
    *(ushort4*)(Wt + n * 1024 + k0 + tx * 4) = w;
  }
}

// bpn[j*4+g]; grid 32 = 4 gates x 8 j-blocks
__global__ __launch_bounds__(256) void fold_bias(
    const float* __restrict__ b0, const float* __restrict__ rx0, const float* __restrict__ P0,
    const float* __restrict__ b1, const float* __restrict__ rx1, const float* __restrict__ P1,
    const float* __restrict__ b2, const float* __restrict__ rx2, const float* __restrict__ P2,
    const float* __restrict__ b3, const float* __restrict__ rx3, const float* __restrict__ P3,
    float* __restrict__ bpn)
{
  const int g = blockIdx.x >> 3, jb = blockIdx.x & 7;
  const float* b  = (g == 0) ? b0  : (g == 1) ? b1  : (g == 2) ? b2  : b3;
  const float* rx = (g == 0) ? rx0 : (g == 1) ? rx1 : (g == 2) ? rx2 : rx3;
  const float* P  = (g == 0) ? P0  : (g == 1) ? P1  : (g == 2) ? P2  : P3;
  __shared__ float bc[512];
  __shared__ float red[4][65];
  const int tid = threadIdx.x;
  bc[tid] = b[tid] * cosf(rx[tid]);
  bc[tid + 256] = b[tid + 256] * cosf(rx[tid + 256]);
  __syncthreads();
  const int jl = tid & 63, msub = tid >> 6;
  const int j = jb * 64 + jl;
  float acc = 0.f;
  for (int m = msub * 128; m < msub * 128 + 128; ++m)
    acc += bc[m] * P[m * 512 + j];
  red[msub][jl] = acc;
  __syncthreads();
  if (msub == 0)
    bpn[j * 4 + g] = red[0][jl] + red[1][jl] + red[2][jl] + red[3][jl];
}

__global__ __launch_bounds__(256) void xcvt_kernel(
    const float* __restrict__ x, u16* __restrict__ xb)
{
  size_t i = (size_t)blockIdx.x * 256 + threadIdx.x;
  f32x4 v = *(const f32x4*)(x + i * 4);
  ushort4 w;
  w.x = f2bf(v[0]); w.y = f2bf(v[1]); w.z = f2bf(v[2]); w.w = f2bf(v[3]);
  *(ushort4*)(xb + i * 4) = w;
}

// zero hbuf + cbuf + flags, every launch (replay determinism)
__global__ __launch_bounds__(256) void init_kernel(unsigned* hbuf32, float* cbuf,
                                                   unsigned* flags) {
  int i = blockIdx.x * 256 + threadIdx.x;      // 65536
  hbuf32[i] = 0;
  cbuf[i] = 0.f;
  if (i < 256) flags[i] = 0;
}

__global__ __launch_bounds__(256) void tail_kernel(
    const float* __restrict__ hlast, const float* __restrict__ c,
    float* __restrict__ hx, float* __restrict__ cx)
{
  int i = blockIdx.x * 256 + threadIdx.x;
  hx[i] = hlast[i];
  cx[i] = c[i];
}

// ---------------------------------------------------------------------------
// fallback single-step kernel (R1-proven)
// ---------------------------------------------------------------------------
__global__ __launch_bounds__(256) void step_kernel(
    const u16* __restrict__ xb_t, const u16* __restrict__ h_in,
    u16* __restrict__ h_out, const u16* __restrict__ Wt,
    const float* __restrict__ bpn, float* __restrict__ cbuf,
    float* __restrict__ out_t)
{
  __shared__ float pre_s[32][33];
  const int bid = blockIdx.x;
  const int mb = bid >> 6, nb = bid & 63;
  const int b0 = mb * 32, n0 = nb * 32;
  const int tid = threadIdx.x;
  const int wv = tid >> 6, lane = tid & 63;
  const int rt = wv >> 1, nt = wv & 1;
  const int l15 = lane & 15, kg = lane >> 4;
  const int brow = b0 + rt * 16 + l15;
  const int ncol = n0 + nt * 16 + l15;
  const u16* wrow = Wt + (size_t)ncol * 1024;
  const u16* xrow = xb_t + (size_t)brow * 512;
  const u16* hrow = h_in + (size_t)brow * 512;
  f32x4 acc = {0.f, 0.f, 0.f, 0.f};
#pragma unroll 8
  for (int kk = 0; kk < 32; ++kk) {
    const int kb = kk * 32 + kg * 8;
    bf16x8 bfrag = *(const bf16x8*)(wrow + kb);
    bf16x8 afrag;
    if (kb < 512) afrag = *(const bf16x8*)(xrow + kb);
    else          afrag = *(const bf16x8*)(hrow + (kb - 512));
    acc = __builtin_amdgcn_mfma_f32_16x16x32_bf16(afrag, bfrag, acc, 0, 0, 0);
  }
  const float bias = bpn[ncol];
#pragma unroll
  for (int q = 0; q < 4; ++q)
    pre_s[rt * 16 + kg * 4 + q][nt * 16 + l15] = acc[q] + bias;
  __syncthreads();
  const int bb = tid >> 3, jo = tid & 7;
  float pf = pre_s[bb][jo * 4 + 0];
  float pi = pre_s[bb][jo * 4 + 1];
  float pu = pre_s[bb][jo * 4 + 2];
  float po = pre_s[bb][jo * 4 + 3];
  float fg = 1.f / (1.f + __expf(-pf));
  float ig = 1.f / (1.f + __expf(-pi));
  float gg = tanhf(pu);
  float og = 1.f / (1.f + __expf(-po));
  size_t idx = (size_t)(b0 + bb) * 512 + (size_t)(nb * 8 + jo);
  float cv = fg * cbuf[idx] + ig * gg;
  cbuf[idx] = cv;
  float hv = og * tanhf(cv);
  out_t[idx] = hv;
  h_out[idx] = f2bf(hv);
}

// ---------------------------------------------------------------------------
// persistent recurrence v6: R7 structure on RAW s_barrier + counted vmcnt
// ledger. All global ops inline-asm (untracked). Per-wave ledger per iter:
//   [issued last iter, oldest first]: out-store(1), x-loads(16)
//   [this iter]: h-loads(16)
//   vmcnt(16) => x landed (hidden under flag/poll/barrier window)
//   vmcnt(0)  => h landed
//   h-store drain = vmcnt(0) with ONLY the 1-dword store outstanding.
// x-loads for t+1 stay in flight across flag-store -> poll -> barrier.
// ---------------------------------------------------------------------------
__global__ __launch_bounds__(256, 1) void qlstm_persistent(
    const u16* __restrict__ Xbf,    // [256][128][512] bf16
    u16* __restrict__ hbuf,         // [2][128][512] bf16
    const u16* __restrict__ Wt,     // [2048][1024] bf16, n = j*4+g
    const float* __restrict__ bpn,  // [2048] f32
    float* __restrict__ out,        // [256][128][512] + hx + cx
    unsigned* __restrict__ flags)   // [256]
{
  __shared__ float pre_s[32][33];
  const int bid = blockIdx.x;
  const int mb = bid >> 6, nb = bid & 63;
  const int b0 = mb * 32, n0 = nb * 32;
  const int tid = threadIdx.x;
  const int wv = tid >> 6, lane = tid & 63;
  const int rt = wv >> 1, nt = wv & 1;
  const int l15 = lane & 15, kg = lane >> 4;
  const int brow = b0 + rt * 16 + l15;
  const int ncol = n0 + nt * 16 + l15;

  // both W halves register-resident (128 VGPR)
  const u16* wrow = Wt + (size_t)ncol * 1024;
  bf16x8 warr[32];
#pragma unroll
  for (int kk = 0; kk < 32; ++kk)
    warr[kk] = *(const bf16x8*)(wrow + kk * 32 + kg * 8);
  const float bnc = bpn[ncol];

  const int bb = tid >> 3, jo = tid & 7;
  const size_t eidx = (size_t)(b0 + bb) * 512 + (size_t)(nb * 8 + jo);
  float cst = 0.f, hl = 0.f;

  // prologue: x-loads for t=0, drained once
  bf16x8 xf[16];
  {
    const u16* xr = Xbf + (size_t)brow * 512;
#pragma unroll
    for (int kk = 0; kk < 16; ++kk)
      ld_g_b128(xr + kk * 32 + kg * 8, xf[kk]);
    asm volatile("s_waitcnt vmcnt(0)" ::: "memory");
  }

  for (int t = 0; t < 256; ++t) {
    // ---- poll (wave 0, one flag per lane); others sail to barrier ----
    if (t > 0 && tid < 64) {
      int guard = 0;
      while (__hip_atomic_load(&flags[mb * 64 + tid], __ATOMIC_RELAXED,
                               __HIP_MEMORY_SCOPE_AGENT) < (unsigned)t) {
        __builtin_amdgcn_s_sleep(1);
        if (++guard > 8000) break;           // bounded: fail loudly, no hang
      }
    }
    __builtin_amdgcn_s_barrier();            // A (no auto-drain)
    asm volatile("" ::: "memory");

    // ---- issue coherent h-loads (fly during x-MFMAs) ----
    bf16x8 hf[16];
    if (t > 0) {
      const u16* hr = hbuf + (size_t)((t & 1) ? 65536 : 0) + (size_t)brow * 512;
#pragma unroll
      for (int kk = 0; kk < 16; ++kk)
        ld_llc_b128(hr + kk * 32 + kg * 8, hf[kk]);
    }

    // ---- x-MFMAs: vmcnt(16) proves the 16 old x-loads landed ----
    asm volatile("s_waitcnt vmcnt(16)" ::: "memory");
    __builtin_amdgcn_sched_barrier(0);
    f32x4 ax0 = {0,0,0,0}, ax1 = {0,0,0,0};
#pragma unroll
    for (int kk = 0; kk < 16; kk += 2) {
      ax0 = __builtin_amdgcn_mfma_f32_16x16x32_bf16(xf[kk],     warr[kk],     ax0, 0, 0, 0);
      ax1 = __builtin_amdgcn_mfma_f32_16x16x32_bf16(xf[kk + 1], warr[kk + 1], ax1, 0, 0, 0);
    }

    // ---- h-MFMAs after vmcnt(0) ----
    f32x4 ah0 = {0,0,0,0}, ah1 = {0,0,0,0};
    if (t > 0) {
      asm volatile("s_waitcnt vmcnt(0)" ::: "memory");
      __builtin_amdgcn_sched_barrier(0);
#pragma unroll
      for (int kk = 0; kk < 16; kk += 2) {
        ah0 = __builtin_amdgcn_mfma_f32_16x16x32_bf16(hf[kk],     warr[16 + kk],     ah0, 0, 0, 0);
        ah1 = __builtin_amdgcn_mfma_f32_16x16x32_bf16(hf[kk + 1], warr[16 + kk + 1], ah1, 0, 0, 0);
      }
    }
    f32x4 acc = (ax0 + ax1) + (ah0 + ah1);

    // ---- LDS gate exchange; C/D: col=lane&15, row=(lane>>4)*4+q ----
#pragma unroll
    for (int q = 0; q < 4; ++q)
      pre_s[rt * 16 + kg * 4 + q][nt * 16 + l15] = acc[q] + bnc;
    asm volatile("s_waitcnt lgkmcnt(0)" ::: "memory");
    __builtin_amdgcn_sched_barrier(0);
    __builtin_amdgcn_s_barrier();            // B
    asm volatile("" ::: "memory");

    // ---- gates + cell update ----
    float pf = pre_s[bb][jo * 4 + 0];
    float pi = pre_s[bb][jo * 4 + 1];
    float pu = pre_s[bb][jo * 4 + 2];
    float po = pre_s[bb][jo * 4 + 3];
    cst = sigm_fast(pf) * cst + sigm_fast(pi) * tanh_fast(pu);
    float hv = sigm_fast(po) * tanh_fast(cst);
    hl = hv;

    // ---- coherent h-store (packed dwords); drain = 1-store ack only ----
    u16 myh = f2bf(hv);
    u32 partner = (u32)(u16)__shfl_xor((int)(u32)myh, 1);
    u16* hnext = hbuf + (size_t)(((t + 1) & 1) ? 65536 : 0);
    if ((tid & 1) == 0)
      st_llc_b32((u32*)(hnext + eidx), (u32)myh | (partner << 16));
    asm volatile("s_waitcnt vmcnt(0)" ::: "memory");
    __builtin_amdgcn_s_barrier();            // C
    asm volatile("" ::: "memory");
    if (tid == 0)
      __hip_atomic_store(&flags[bid], (unsigned)(t + 1), __ATOMIC_RELAXED,
                         __HIP_MEMORY_SCOPE_AGENT);

    // ---- post-flag: out-store(1) then x-loads(16) — stay in flight ----
    union { float f; u32 u; } ho; ho.f = hv;
    st_g_b32((u32*)(out + (size_t)t * 65536 + eidx), ho.u);
    if (t < 255) {
      const u16* xr = Xbf + (size_t)(t + 1) * 65536 + (size_t)brow * 512;
#pragma unroll
      for (int kk = 0; kk < 16; ++kk)
        ld_g_b128(xr + kk * 32 + kg * 8, xf[kk]);
    }
  }

  asm volatile("s_waitcnt vmcnt(0)" ::: "memory");
  out[(size_t)256 * 65536 + eidx] = hl;
  out[(size_t)256 * 65536 + 65536 + eidx] = cst;
}

// ---------------------------------------------------------------------------
extern "C" void kernel_launch(void* const* d_in, const int* in_sizes, int n_in,
                              void* d_out, int out_size, void* d_ws, size_t ws_size,
                              hipStream_t stream) {
  (void)in_sizes; (void)n_in; (void)out_size; (void)ws_size;
  const float* inp = (const float*)d_in[0];
  float* out = (float*)d_out;

  char* base = (char*)d_ws;
  u16*      Xbf   = (u16*)base;
  u16*      Wt    = (u16*)(base + 33554432);
  float*    bpn   = (float*)(base + 33554432 + 4194304);
  u16*      hbuf  = (u16*)(base + 33554432 + 4194304 + 8192);
  unsigned* flags = (unsigned*)(base + 33554432 + 4194304 + 8192 + 262144);
  float*    cbuf  = (float*)(base + 33554432 + 4194304 + 8192 + 262144 + 1024);

  const float* W[4];  const float* b[4];  const float* rx[4];  const float* P[4];
  for (int g = 0; g < 4; ++g) {
    W[g]  = (const float*)d_in[1 + 4 * g];
    b[g]  = (const float*)d_in[2 + 4 * g];
    rx[g] = (const float*)d_in[3 + 4 * g];
    P[g]  = (const float*)d_in[4 + 4 * g];
  }
  fold_kernel<<<dim3(16, 8, 4), 256, 0, stream>>>(
      W[0], rx[0], P[0], W[1], rx[1], P[1],
      W[2], rx[2], P[2], W[3], rx[3], P[3], Wt);
  fold_bias<<<dim3(32), 256, 0, stream>>>(
      b[0], rx[0], P[0], b[1], rx[1], P[1],
      b[2], rx[2], P[2], b[3], rx[3], P[3], bpn);
  xcvt_kernel<<<16384, 256, 0, stream>>>(inp, Xbf);
  init_kernel<<<256, 256, 0, stream>>>((unsigned*)hbuf, cbuf, flags);

  void* args[6];
  const u16* Xbf_c = Xbf;
  const u16* Wt_c = Wt;
  const float* bpn_c = bpn;
  u16* hbuf_p = hbuf;
  float* out_p = out;
  unsigned* flags_p = flags;
  args[0] = (void*)&Xbf_c;
  args[1] = (void*)&hbuf_p;
  args[2] = (void*)&Wt_c;
  args[3] = (void*)&bpn_c;
  args[4] = (void*)&out_p;
  args[5] = (void*)&flags_p;
  hipError_t e = hipLaunchCooperativeKernel((const void*)qlstm_persistent,
                                            dim3(256), dim3(256), args, 0, stream);
  if (e != hipSuccess) {
    for (int t = 0; t < 256; ++t) {
      const u16* xb_t  = Xbf + (size_t)t * 65536;
      const u16* h_in  = hbuf + (size_t)(t & 1) * 65536;
      u16*       h_oup = hbuf + (size_t)((t & 1) ^ 1) * 65536;
      float*     out_t = out + (size_t)t * 65536;
      step_kernel<<<256, 256, 0, stream>>>(xb_t, h_in, h_oup, Wt, bpn, cbuf, out_t);
    }
    tail_kernel<<<256, 256, 0, stream>>>(out + (size_t)255 * 65536, cbuf,
                                         out + (size_t)256 * 65536,
                                         out + (size_t)256 * 65536 + 65536);
  }
}